// Round 4
// baseline (4373.904 us; speedup 1.0000x reference)
//
#include <hip/hip_runtime.h>
#include <stdint.h>

#define MB 16   // batch rows per group
#define GW 16   // workgroups per group
#define NU 32   // hidden units per WG
#define HD 512
#define SEQ 512
#define DX 40
#define WPS 4096  // 8B tagged words per exchange slot (16*512/2)

using short8 = __attribute__((ext_vector_type(8))) short;
using f32x4  = __attribute__((ext_vector_type(4))) float;

__device__ __forceinline__ unsigned short f2bf(float f) {
  uint32_t u = __builtin_bit_cast(uint32_t, f);
  u += 0x7fffu + ((u >> 16) & 1u);
  return (unsigned short)(u >> 16);
}
__device__ __forceinline__ float sigm(float x) { return 1.0f / (1.0f + __expf(-x)); }

// h exchange: 8B tagged words {lo32: 2 x bf16 h, hi32: step tag}, agent-scope
// relaxed atomics (sc0 sc1 -> LLC write-through / LLC-direct read). Consumers
// poll the data words themselves: detection IS the load. Double-buffered by
// step parity; tag >= t accepts. No flags, no fences, 2 barriers per step.

// ---------------- GRU persistent kernel ----------------
// grid = 64 (4 groups x 16 WGs), 512 threads. Waves 0..5: MFMA (r,z,n x 2 unit
// tiles; n-gate has zero x-fragments). Waves 6,7: xn = x @ Wn^T via 2 MFMAs
// (separate because n = tanh(xn + r*hn)).
__global__ __launch_bounds__(512, 2) void gru_kernel(
    const float* __restrict__ x, const float* __restrict__ Wih,
    const float* __restrict__ Whh, const float* __restrict__ bih,
    const float* __restrict__ bhh, unsigned long long* __restrict__ hbuf,
    float* __restrict__ o1, float* __restrict__ stats)
{
  const int wg = blockIdx.x & (GW - 1);
  const int g  = blockIdx.x >> 4;
  const int tid = threadIdx.x;
  const int wave = tid >> 6;
  const int lane = tid & 63;
  const int u0 = wg * NU;
  const int bg = g * MB;

  __shared__ unsigned short h_s[MB][520];  // bf16 h tile
  __shared__ unsigned short x_s[MB][72];   // 0..39 x, 40..63 zero (K-pad)
  __shared__ float gate_s[3][MB][NU];
  __shared__ float xn_s[MB][NU];

  for (int i = tid; i < MB * 32; i += 512) x_s[i >> 5][40 + (i & 31)] = 0;

  // weight B-fragments in registers. B[k][n]: n=lane&15, k=(lane>>4)*8+j.
  short8 bfrag[18];
  const int myGate = wave >> 1;
  const int ut = wave & 1;
  const int kq = (lane >> 4) * 8;
  if (wave < 6) {
    const int row = myGate * HD + u0 + ut * 16 + (lane & 15);
    for (int kt = 0; kt < 16; ++kt) {
      const float* p = Whh + (size_t)row * HD + kt * 32 + kq;
      short8 f;
#pragma unroll
      for (int j = 0; j < 8; ++j) f[j] = (short)f2bf(p[j]);
      bfrag[kt] = f;
    }
    for (int kt = 16; kt < 18; ++kt) {     // x cols: r,z only (n via xn MFMA)
      short8 f;
#pragma unroll
      for (int j = 0; j < 8; ++j) {
        int c = kt * 32 + kq + j - HD;
        float v = (myGate < 2 && c < DX) ? Wih[(size_t)row * DX + c] : 0.0f;
        f[j] = (short)f2bf(v);
      }
      bfrag[kt] = f;
    }
  } else {                                 // waves 6,7: Wn fragments, K=64 pad
    const int row = 2 * HD + u0 + (wave - 6) * 16 + (lane & 15);
    for (int kt = 0; kt < 2; ++kt) {
      short8 f;
#pragma unroll
      for (int j = 0; j < 8; ++j) {
        int c = kt * 32 + kq + j;
        f[j] = (short)((c < DX) ? f2bf(Wih[(size_t)row * DX + c]) : 0);
      }
      bfrag[kt] = f;
    }
  }

  const int sb = tid >> 5;
  const int su = tid & 31;
  float hprev = 0.0f, ssum = 0.0f, ssq = 0.0f;
  const float b_r  = bih[u0 + su] + bhh[u0 + su];
  const float b_z  = bih[HD + u0 + su] + bhh[HD + u0 + su];
  const float b_in = bih[2 * HD + u0 + su];
  const float b_hn = bhh[2 * HD + u0 + su];

  for (int t = 0; t < SEQ; ++t) {
    const unsigned long long* slot = hbuf + ((size_t)g * 2 + (t & 1)) * WPS;
    unsigned long long* oslot      = hbuf + ((size_t)g * 2 + ((t + 1) & 1)) * WPS;

    {  // poll+stage h(t): 8 tagged words/thread, issue all then retry misses
      unsigned long long w[8];
#pragma unroll
      for (int it = 0; it < 8; ++it)
        w[it] = __hip_atomic_load(slot + it * 512 + tid, __ATOMIC_RELAXED,
                                  __HIP_MEMORY_SCOPE_AGENT);
#pragma unroll
      for (int it = 0; it < 8; ++it) {
        while ((unsigned)(w[it] >> 32) < (unsigned)t) {
          __builtin_amdgcn_s_sleep(1);
          w[it] = __hip_atomic_load(slot + it * 512 + tid, __ATOMIC_RELAXED,
                                    __HIP_MEMORY_SCOPE_AGENT);
        }
        int q = it * 512 + tid;
        *(uint32_t*)(&h_s[q >> 8][(q & 255) * 2]) = (uint32_t)w[it];
      }
    }
    {  // stage x_t
      int b = tid >> 5, c = tid & 31;
      const float* xr = x + ((size_t)(bg + b) * SEQ + t) * DX;
      x_s[b][c] = f2bf(xr[c]);
      if (c < 8) x_s[b][32 + c] = f2bf(xr[32 + c]);
    }
    __syncthreads();  // B: h_s, x_s ready; gate_s/xn_s of t-1 fully consumed

    if (wave < 6) {
      const int m = lane & 15;
      f32x4 acc = {0.f, 0.f, 0.f, 0.f};
#pragma unroll
      for (int kt = 0; kt < 16; ++kt) {
        short8 a = *(const short8*)(&h_s[m][kt * 32 + kq]);
        acc = __builtin_amdgcn_mfma_f32_16x16x32_bf16(a, bfrag[kt], acc, 0, 0, 0);
      }
      short8 ax0 = *(const short8*)(&x_s[m][kq]);
      short8 ax1 = *(const short8*)(&x_s[m][32 + kq]);
      acc = __builtin_amdgcn_mfma_f32_16x16x32_bf16(ax0, bfrag[16], acc, 0, 0, 0);
      acc = __builtin_amdgcn_mfma_f32_16x16x32_bf16(ax1, bfrag[17], acc, 0, 0, 0);
#pragma unroll
      for (int r = 0; r < 4; ++r)          // C/D: col=lane&15, row=(lane>>4)*4+r
        gate_s[myGate][(lane >> 4) * 4 + r][ut * 16 + (lane & 15)] = acc[r];
    } else {                               // xn via MFMA
      const int m = lane & 15;
      f32x4 acc = {0.f, 0.f, 0.f, 0.f};
      short8 ax0 = *(const short8*)(&x_s[m][kq]);
      short8 ax1 = *(const short8*)(&x_s[m][32 + kq]);
      acc = __builtin_amdgcn_mfma_f32_16x16x32_bf16(ax0, bfrag[0], acc, 0, 0, 0);
      acc = __builtin_amdgcn_mfma_f32_16x16x32_bf16(ax1, bfrag[1], acc, 0, 0, 0);
#pragma unroll
      for (int r = 0; r < 4; ++r)
        xn_s[(lane >> 4) * 4 + r][(wave - 6) * 16 + (lane & 15)] = acc[r];
    }
    __syncthreads();  // C: gates + xn ready

    float r_ = sigm(gate_s[0][sb][su] + b_r);
    float z_ = sigm(gate_s[1][sb][su] + b_z);
    float n_ = tanhf(xn_s[sb][su] + b_in + r_ * (gate_s[2][sb][su] + b_hn));
    float h = (1.0f - z_) * n_ + z_ * hprev;
    hprev = h;
    ssum += h; ssq += h * h;
    {  // tagged publish: even threads store {h pair, t+1}
      float hp = __shfl_xor(h, 1);
      if ((tid & 1) == 0) {
        uint32_t pair = (uint32_t)f2bf(h) | ((uint32_t)f2bf(hp) << 16);
        unsigned long long w =
            (unsigned long long)pair | ((unsigned long long)(t + 1) << 32);
        __hip_atomic_store(oslot + ((sb * HD + u0 + su) >> 1), w,
                           __ATOMIC_RELAXED, __HIP_MEMORY_SCOPE_AGENT);
      }
    }
    o1[((size_t)(bg + sb) * SEQ + t) * HD + u0 + su] = h;
  }

  atomicAdd(&stats[u0 + su], ssum);
  atomicAdd(&stats[HD + u0 + su], ssq);
}

// ---------------- LSTM persistent kernel ----------------
// 8 MFMA waves (i,f,g,o x 2 unit tiles); x(40)+ssr(1) folded into K-tiles 16,17.
__global__ __launch_bounds__(512, 2) void lstm_kernel(
    const float* __restrict__ x, const float* __restrict__ Wih,
    const float* __restrict__ Whh, const float* __restrict__ bih,
    const float* __restrict__ bhh, const float* __restrict__ ssr,
    unsigned long long* __restrict__ hbuf, float* __restrict__ o2)
{
  const int wg = blockIdx.x & (GW - 1);
  const int g  = blockIdx.x >> 4;
  const int tid = threadIdx.x;
  const int wave = tid >> 6;
  const int lane = tid & 63;
  const int u0 = wg * NU;
  const int bg = g * MB;

  __shared__ unsigned short h_s[MB][520];
  __shared__ unsigned short x_s[MB][72];   // 0..39 x, 40 ssr, 41..63 zero
  __shared__ float gate_s[4][MB][NU];

  for (int i = tid; i < MB * 32; i += 512) x_s[i >> 5][40 + (i & 31)] = 0;

  short8 bfrag[18];
  const int myGate = wave >> 1;
  const int ut = wave & 1;
  const int kq = (lane >> 4) * 8;
  {
    const int row = myGate * HD + u0 + ut * 16 + (lane & 15);
    for (int kt = 0; kt < 16; ++kt) {
      const float* p = Whh + (size_t)row * HD + kt * 32 + kq;
      short8 f;
#pragma unroll
      for (int j = 0; j < 8; ++j) f[j] = (short)f2bf(p[j]);
      bfrag[kt] = f;
    }
    for (int kt = 16; kt < 18; ++kt) {     // Wih has 41 cols (x, ssr)
      short8 f;
#pragma unroll
      for (int j = 0; j < 8; ++j) {
        int c = kt * 32 + kq + j - HD;
        float v = (c < 41) ? Wih[(size_t)row * 41 + c] : 0.0f;
        f[j] = (short)f2bf(v);
      }
      bfrag[kt] = f;
    }
  }

  const int sb = tid >> 5;
  const int su = tid & 31;
  float creg = 0.0f;
  const float b_i = bih[u0 + su] + bhh[u0 + su];
  const float b_f = bih[HD + u0 + su] + bhh[HD + u0 + su];
  const float b_g = bih[2 * HD + u0 + su] + bhh[2 * HD + u0 + su];
  const float b_o = bih[3 * HD + u0 + su] + bhh[3 * HD + u0 + su];

  for (int t = 0; t < SEQ; ++t) {
    const unsigned long long* slot = hbuf + ((size_t)g * 2 + (t & 1)) * WPS;
    unsigned long long* oslot      = hbuf + ((size_t)g * 2 + ((t + 1) & 1)) * WPS;

    {
      unsigned long long w[8];
#pragma unroll
      for (int it = 0; it < 8; ++it)
        w[it] = __hip_atomic_load(slot + it * 512 + tid, __ATOMIC_RELAXED,
                                  __HIP_MEMORY_SCOPE_AGENT);
#pragma unroll
      for (int it = 0; it < 8; ++it) {
        while ((unsigned)(w[it] >> 32) < (unsigned)t) {
          __builtin_amdgcn_s_sleep(1);
          w[it] = __hip_atomic_load(slot + it * 512 + tid, __ATOMIC_RELAXED,
                                    __HIP_MEMORY_SCOPE_AGENT);
        }
        int q = it * 512 + tid;
        *(uint32_t*)(&h_s[q >> 8][(q & 255) * 2]) = (uint32_t)w[it];
      }
    }
    {
      int b = tid >> 5, c = tid & 31;
      const float* xr = x + ((size_t)(bg + b) * SEQ + t) * DX;
      x_s[b][c] = f2bf(xr[c]);
      if (c < 8) x_s[b][32 + c] = f2bf(xr[32 + c]);
      if (c == 8) x_s[b][40] = f2bf(ssr[(size_t)(bg + b) * SEQ + t]);
    }
    __syncthreads();  // B

    {
      const int m = lane & 15;
      f32x4 acc = {0.f, 0.f, 0.f, 0.f};
#pragma unroll
      for (int kt = 0; kt < 16; ++kt) {
        short8 a = *(const short8*)(&h_s[m][kt * 32 + kq]);
        acc = __builtin_amdgcn_mfma_f32_16x16x32_bf16(a, bfrag[kt], acc, 0, 0, 0);
      }
      short8 ax0 = *(const short8*)(&x_s[m][kq]);
      short8 ax1 = *(const short8*)(&x_s[m][32 + kq]);
      acc = __builtin_amdgcn_mfma_f32_16x16x32_bf16(ax0, bfrag[16], acc, 0, 0, 0);
      acc = __builtin_amdgcn_mfma_f32_16x16x32_bf16(ax1, bfrag[17], acc, 0, 0, 0);
#pragma unroll
      for (int r = 0; r < 4; ++r)
        gate_s[myGate][(lane >> 4) * 4 + r][ut * 16 + (lane & 15)] = acc[r];
    }
    __syncthreads();  // C

    float gi = sigm(gate_s[0][sb][su] + b_i);
    float gf_ = sigm(gate_s[1][sb][su] + b_f);
    float gg = tanhf(gate_s[2][sb][su] + b_g);
    float go = sigm(gate_s[3][sb][su] + b_o);
    creg = gf_ * creg + gi * gg;
    float h = go * tanhf(creg);
    {
      float hp = __shfl_xor(h, 1);
      if ((tid & 1) == 0) {
        uint32_t pair = (uint32_t)f2bf(h) | ((uint32_t)f2bf(hp) << 16);
        unsigned long long w =
            (unsigned long long)pair | ((unsigned long long)(t + 1) << 32);
        __hip_atomic_store(oslot + ((sb * HD + u0 + su) >> 1), w,
                           __ATOMIC_RELAXED, __HIP_MEMORY_SCOPE_AGENT);
      }
    }
    o2[((size_t)(bg + sb) * SEQ + t) * HD + u0 + su] = h;
  }
}

// ---------------- BN-coefficient kernel (1 block) ----------------
__global__ __launch_bounds__(512) void coef_kernel(
    const float* __restrict__ stats, const float* __restrict__ fc1_w,
    const float* __restrict__ fc1_b, const float* __restrict__ fc2_w,
    const float* __restrict__ fc2_b, const float* __restrict__ gamma,
    const float* __restrict__ beta, float* __restrict__ coef)
{
  __shared__ float r1[512], r2[512];
  const int j = threadIdx.x;
  const float inv_n = 1.0f / 32768.0f;
  float mean = stats[j] * inv_n;
  float var = stats[HD + j] * inv_n - mean * mean;
  float scale = gamma[j] * rsqrtf(var + 1e-5f);
  float shift = beta[j] - mean * scale;
  coef[j] = fc1_w[j] * scale;
  coef[HD + j] = fc2_w[j] * scale;
  r1[j] = fc1_w[j] * shift;
  r2[j] = fc2_w[j] * shift;
  __syncthreads();
  for (int s = 256; s > 0; s >>= 1) {
    if (j < s) { r1[j] += r1[j + s]; r2[j] += r2[j + s]; }
    __syncthreads();
  }
  if (j == 0) {
    coef[2 * HD] = r1[0] + fc1_b[0];
    coef[2 * HD + 1] = r2[0] + fc2_b[0];
  }
}

// ---------------- ssr kernel: one wave per (b,t) row ----------------
__global__ __launch_bounds__(256) void ssr_kernel(
    const float* __restrict__ o1, const float* __restrict__ coef,
    float* __restrict__ ssr_ws, float* __restrict__ dssr)
{
  const int row = blockIdx.x * 4 + (threadIdx.x >> 6);
  const int lane = threadIdx.x & 63;
  const float* p = o1 + (size_t)row * HD + lane * 8;
  float s1 = 0.f, s2 = 0.f;
#pragma unroll
  for (int j = 0; j < 8; ++j) {
    float v = p[j];
    s1 += v * coef[lane * 8 + j];
    s2 += v * coef[HD + lane * 8 + j];
  }
#pragma unroll
  for (int off = 32; off > 0; off >>= 1) {
    s1 += __shfl_down(s1, off);
    s2 += __shfl_down(s2, off);
  }
  if (lane == 0) {
    float sr = fmaxf(s1 + coef[2 * HD], 0.0f);
    float w = fabsf(sigm(s2 + coef[2 * HD + 1]));
    float v = sr * (1.0f + w);
    ssr_ws[row] = v;
    dssr[row] = v;
  }
}

// ---------------- fc3 output kernel ----------------
__global__ __launch_bounds__(256) void out_kernel(
    const float* __restrict__ o2, const float* __restrict__ fc3_w,
    const float* __restrict__ fc3_b, float* __restrict__ dout)
{
  const int row = blockIdx.x * 4 + (threadIdx.x >> 6);
  const int lane = threadIdx.x & 63;
  const float* p = o2 + (size_t)row * HD + lane * 8;
  float s = 0.f;
#pragma unroll
  for (int j = 0; j < 8; ++j) s += p[j] * fc3_w[lane * 8 + j];
#pragma unroll
  for (int off = 32; off > 0; off >>= 1) s += __shfl_down(s, off);
  if (lane == 0) dout[row] = fmaxf(s + fc3_b[0], 0.0f);
}

extern "C" void kernel_launch(void* const* d_in, const int* in_sizes, int n_in,
                              void* d_out, int out_size, void* d_ws, size_t ws_size,
                              hipStream_t stream) {
  (void)in_sizes; (void)n_in; (void)out_size; (void)ws_size;
  const float* x    = (const float*)d_in[0];
  const float* gWih = (const float*)d_in[1];
  const float* gWhh = (const float*)d_in[2];
  const float* gbih = (const float*)d_in[3];
  const float* gbhh = (const float*)d_in[4];
  const float* lWih = (const float*)d_in[5];
  const float* lWhh = (const float*)d_in[6];
  const float* lbih = (const float*)d_in[7];
  const float* lbhh = (const float*)d_in[8];
  const float* fc1w = (const float*)d_in[9];
  const float* fc1b = (const float*)d_in[10];
  const float* fc2w = (const float*)d_in[11];
  const float* fc2b = (const float*)d_in[12];
  const float* fc3w = (const float*)d_in[13];
  const float* fc3b = (const float*)d_in[14];
  const float* gam  = (const float*)d_in[15];
  const float* bet  = (const float*)d_in[16];
  float* out = (float*)d_out;

  char* ws = (char*)d_ws;
  float* stats = (float*)(ws + 8192);                 // 1024 f32
  float* coef  = (float*)(ws + 16384);                // 1026 f32
  float* ssr_ws = (float*)(ws + 32768);               // 32768 f32
  unsigned long long* hbuf_g = (unsigned long long*)(ws + 262144);  // 256KB
  unsigned long long* hbuf_l = (unsigned long long*)(ws + 524288);  // 256KB
  float* o1 = (float*)(ws + 1048576);                 // 64MB
  float* o2 = o1 + (size_t)64 * SEQ * HD;             // 64MB

  hipMemsetAsync(ws + 8192, 0, 4096, stream);         // stats
  hipMemsetAsync(ws + 262144, 0, 524288, stream);     // exchange slots (h0=0,tag0)

  gru_kernel<<<dim3(64), dim3(512), 0, stream>>>(x, gWih, gWhh, gbih, gbhh,
                                                 hbuf_g, o1, stats);
  coef_kernel<<<dim3(1), dim3(512), 0, stream>>>(stats, fc1w, fc1b, fc2w, fc2b,
                                                 gam, bet, coef);
  ssr_kernel<<<dim3(8192), dim3(256), 0, stream>>>(o1, coef, ssr_ws, out + 32768);
  lstm_kernel<<<dim3(64), dim3(512), 0, stream>>>(x, lWih, lWhh, lbih, lbhh, ssr_ws,
                                                  hbuf_l, o2);
  out_kernel<<<dim3(8192), dim3(256), 0, stream>>>(o2, fc3w, fc3b, out);
}

// Round 5
// 3303.997 us; speedup vs baseline: 1.3238x; 1.3238x over previous
//
#include <hip/hip_runtime.h>
#include <stdint.h>

#define MB 16   // batch rows per group
#define GW 16   // workgroups per group
#define NU 32   // hidden units per WG
#define HD 512
#define SEQ 512
#define DX 40

using short8 = __attribute__((ext_vector_type(8))) short;
using f32x4  = __attribute__((ext_vector_type(4))) float;

__device__ __forceinline__ unsigned short f2bf(float f) {
  uint32_t u = __builtin_bit_cast(uint32_t, f);
  u += 0x7fffu + ((u >> 16) & 1u);
  return (unsigned short)(u >> 16);
}
__device__ __forceinline__ float sigm(float x) { return 1.0f / (1.0f + __expf(-x)); }

// h exchange protocol (R3-style, best measured):
//  - h pairs: bf16x2 in 4B words, __hip_atomic_store relaxed AGENT (sc0 sc1,
//    write-through to LLC). __syncthreads drains vmcnt -> data at LLC before
//    the per-WG flag store. No threadfence, no cache invalidates.
//  - fused poll: every staging thread's 4x8B chunks come from ONE producer
//    ((tid&127)>>3), so it polls that producer's flag then loads immediately.
//    16 distinct flag lines only -> wave-coalesced broadcast, tiny traffic.

// ---------------- GRU persistent kernel ----------------
// grid = 64 (4 groups x 16 WGs), 512 threads. Waves 0..5: MFMA (r,z,n x 2 unit
// tiles; n-gate x-fragments are zero). Waves 6,7: xn = x @ Wn^T via 2 MFMAs
// (kept separate because n = tanh(xn + r*hn)).
__global__ __launch_bounds__(512, 2) void gru_kernel(
    const float* __restrict__ x, const float* __restrict__ Wih,
    const float* __restrict__ Whh, const float* __restrict__ bih,
    const float* __restrict__ bhh, unsigned* __restrict__ flags,
    unsigned short* __restrict__ hbuf, float* __restrict__ o1,
    float* __restrict__ stats)
{
  const int wg = blockIdx.x & (GW - 1);
  const int g  = blockIdx.x >> 4;
  const int tid = threadIdx.x;
  const int wave = tid >> 6;
  const int lane = tid & 63;
  const int u0 = wg * NU;
  const int bg = g * MB;

  __shared__ unsigned short h_s[MB][520];  // bf16 h tile
  __shared__ unsigned short x_s[MB][72];   // 0..39 x, 40..63 zero (K-pad)
  __shared__ float gate_s[3][MB][NU];
  __shared__ float xn_s[MB][NU];

  for (int i = tid; i < MB * 32; i += 512) x_s[i >> 5][40 + (i & 31)] = 0;

  // weight B-fragments in registers. B[k][n]: n=lane&15, k=(lane>>4)*8+j.
  short8 bfrag[18];
  const int myGate = wave >> 1;
  const int ut = wave & 1;
  const int kq = (lane >> 4) * 8;
  if (wave < 6) {
    const int row = myGate * HD + u0 + ut * 16 + (lane & 15);
    for (int kt = 0; kt < 16; ++kt) {
      const float* p = Whh + (size_t)row * HD + kt * 32 + kq;
      short8 f;
#pragma unroll
      for (int j = 0; j < 8; ++j) f[j] = (short)f2bf(p[j]);
      bfrag[kt] = f;
    }
    for (int kt = 16; kt < 18; ++kt) {     // x cols: r,z only (n via xn MFMA)
      short8 f;
#pragma unroll
      for (int j = 0; j < 8; ++j) {
        int c = kt * 32 + kq + j - HD;
        float v = (myGate < 2 && c < DX) ? Wih[(size_t)row * DX + c] : 0.0f;
        f[j] = (short)f2bf(v);
      }
      bfrag[kt] = f;
    }
  } else {                                 // waves 6,7: Wn fragments, K=64 pad
    const int row = 2 * HD + u0 + (wave - 6) * 16 + (lane & 15);
    for (int kt = 0; kt < 2; ++kt) {
      short8 f;
#pragma unroll
      for (int j = 0; j < 8; ++j) {
        int c = kt * 32 + kq + j;
        f[j] = (short)((c < DX) ? f2bf(Wih[(size_t)row * DX + c]) : 0);
      }
      bfrag[kt] = f;
    }
  }

  const int sb = tid >> 5;
  const int su = tid & 31;
  float hprev = 0.0f, ssum = 0.0f, ssq = 0.0f;
  const float b_r  = bih[u0 + su] + bhh[u0 + su];
  const float b_z  = bih[HD + u0 + su] + bhh[HD + u0 + su];
  const float b_in = bih[2 * HD + u0 + su];
  const float b_hn = bhh[2 * HD + u0 + su];

  unsigned* gf = flags + g * GW * 16;              // 64B-strided per-WG flags
  unsigned* myProdFlag = gf + ((tid & 127) >> 3) * 16;  // this thread's producer

  for (int t = 0; t < SEQ; ++t) {
    const unsigned long long* hin64 =
        (const unsigned long long*)(hbuf + ((size_t)g * 2 + (t & 1)) * MB * HD);
    uint32_t* hout32 =
        (uint32_t*)(hbuf + ((size_t)g * 2 + ((t + 1) & 1)) * MB * HD);

    {  // fused poll + stage: wait for my producer, then load my 4 chunks
      while (__hip_atomic_load(myProdFlag, __ATOMIC_RELAXED,
                               __HIP_MEMORY_SCOPE_AGENT) < (unsigned)t)
        __builtin_amdgcn_s_sleep(1);
#pragma unroll
      for (int it = 0; it < 4; ++it) {
        int q = it * 512 + tid;            // 8B-word index into 16KB tile
        unsigned long long v = __hip_atomic_load(hin64 + q, __ATOMIC_RELAXED,
                                                 __HIP_MEMORY_SCOPE_AGENT);
        *(unsigned long long*)(&h_s[q >> 7][(q & 127) * 4]) = v;
      }
    }
    {  // stage x_t
      int b = tid >> 5, c = tid & 31;
      const float* xr = x + ((size_t)(bg + b) * SEQ + t) * DX;
      x_s[b][c] = f2bf(xr[c]);
      if (c < 8) x_s[b][32 + c] = f2bf(xr[32 + c]);
    }
    __syncthreads();  // B: h_s, x_s ready (and all 16 flags >= t block-wide)

    if (wave < 6) {
      const int m = lane & 15;
      f32x4 acc = {0.f, 0.f, 0.f, 0.f};
#pragma unroll
      for (int kt = 0; kt < 16; ++kt) {
        short8 a = *(const short8*)(&h_s[m][kt * 32 + kq]);
        acc = __builtin_amdgcn_mfma_f32_16x16x32_bf16(a, bfrag[kt], acc, 0, 0, 0);
      }
      short8 ax0 = *(const short8*)(&x_s[m][kq]);
      short8 ax1 = *(const short8*)(&x_s[m][32 + kq]);
      acc = __builtin_amdgcn_mfma_f32_16x16x32_bf16(ax0, bfrag[16], acc, 0, 0, 0);
      acc = __builtin_amdgcn_mfma_f32_16x16x32_bf16(ax1, bfrag[17], acc, 0, 0, 0);
#pragma unroll
      for (int r = 0; r < 4; ++r)          // C/D: col=lane&15, row=(lane>>4)*4+r
        gate_s[myGate][(lane >> 4) * 4 + r][ut * 16 + (lane & 15)] = acc[r];
    } else {                               // xn via MFMA
      const int m = lane & 15;
      f32x4 acc = {0.f, 0.f, 0.f, 0.f};
      short8 ax0 = *(const short8*)(&x_s[m][kq]);
      short8 ax1 = *(const short8*)(&x_s[m][32 + kq]);
      acc = __builtin_amdgcn_mfma_f32_16x16x32_bf16(ax0, bfrag[0], acc, 0, 0, 0);
      acc = __builtin_amdgcn_mfma_f32_16x16x32_bf16(ax1, bfrag[1], acc, 0, 0, 0);
#pragma unroll
      for (int r = 0; r < 4; ++r)
        xn_s[(lane >> 4) * 4 + r][(wave - 6) * 16 + (lane & 15)] = acc[r];
    }
    __syncthreads();  // C: gates + xn ready

    float r_ = sigm(gate_s[0][sb][su] + b_r);
    float z_ = sigm(gate_s[1][sb][su] + b_z);
    float n_ = tanhf(xn_s[sb][su] + b_in + r_ * (gate_s[2][sb][su] + b_hn));
    float h = (1.0f - z_) * n_ + z_ * hprev;
    hprev = h;
    ssum += h; ssq += h * h;
    {  // pack bf16x2 with lane partner, even threads write-through to LLC
      float hp = __shfl_xor(h, 1);
      if ((tid & 1) == 0) {
        uint32_t packed = (uint32_t)f2bf(h) | ((uint32_t)f2bf(hp) << 16);
        __hip_atomic_store(hout32 + ((sb * HD + u0 + su) >> 1), packed,
                           __ATOMIC_RELAXED, __HIP_MEMORY_SCOPE_AGENT);
      }
    }
    __syncthreads();  // D: drains vmcnt -> hout committed at LLC

    if (tid == 0)
      __hip_atomic_store(gf + wg * 16, (unsigned)(t + 1), __ATOMIC_RELAXED,
                         __HIP_MEMORY_SCOPE_AGENT);
    o1[((size_t)(bg + sb) * SEQ + t) * HD + u0 + su] = h;
  }

  atomicAdd(&stats[u0 + su], ssum);
  atomicAdd(&stats[HD + u0 + su], ssq);
}

// ---------------- LSTM persistent kernel ----------------
// 8 MFMA waves (i,f,g,o x 2 unit tiles); x(40)+ssr(1) folded into K-tiles 16,17.
__global__ __launch_bounds__(512, 2) void lstm_kernel(
    const float* __restrict__ x, const float* __restrict__ Wih,
    const float* __restrict__ Whh, const float* __restrict__ bih,
    const float* __restrict__ bhh, const float* __restrict__ ssr,
    unsigned* __restrict__ flags, unsigned short* __restrict__ hbuf,
    float* __restrict__ o2)
{
  const int wg = blockIdx.x & (GW - 1);
  const int g  = blockIdx.x >> 4;
  const int tid = threadIdx.x;
  const int wave = tid >> 6;
  const int lane = tid & 63;
  const int u0 = wg * NU;
  const int bg = g * MB;

  __shared__ unsigned short h_s[MB][520];
  __shared__ unsigned short x_s[MB][72];   // 0..39 x, 40 ssr, 41..63 zero
  __shared__ float gate_s[4][MB][NU];

  for (int i = tid; i < MB * 32; i += 512) x_s[i >> 5][40 + (i & 31)] = 0;

  short8 bfrag[18];
  const int myGate = wave >> 1;
  const int ut = wave & 1;
  const int kq = (lane >> 4) * 8;
  {
    const int row = myGate * HD + u0 + ut * 16 + (lane & 15);
    for (int kt = 0; kt < 16; ++kt) {
      const float* p = Whh + (size_t)row * HD + kt * 32 + kq;
      short8 f;
#pragma unroll
      for (int j = 0; j < 8; ++j) f[j] = (short)f2bf(p[j]);
      bfrag[kt] = f;
    }
    for (int kt = 16; kt < 18; ++kt) {     // Wih has 41 cols (x, ssr)
      short8 f;
#pragma unroll
      for (int j = 0; j < 8; ++j) {
        int c = kt * 32 + kq + j - HD;
        float v = (c < 41) ? Wih[(size_t)row * 41 + c] : 0.0f;
        f[j] = (short)f2bf(v);
      }
      bfrag[kt] = f;
    }
  }

  const int sb = tid >> 5;
  const int su = tid & 31;
  float creg = 0.0f;
  const float b_i = bih[u0 + su] + bhh[u0 + su];
  const float b_f = bih[HD + u0 + su] + bhh[HD + u0 + su];
  const float b_g = bih[2 * HD + u0 + su] + bhh[2 * HD + u0 + su];
  const float b_o = bih[3 * HD + u0 + su] + bhh[3 * HD + u0 + su];

  unsigned* gf = flags + g * GW * 16;
  unsigned* myProdFlag = gf + ((tid & 127) >> 3) * 16;

  for (int t = 0; t < SEQ; ++t) {
    const unsigned long long* hin64 =
        (const unsigned long long*)(hbuf + ((size_t)g * 2 + (t & 1)) * MB * HD);
    uint32_t* hout32 =
        (uint32_t*)(hbuf + ((size_t)g * 2 + ((t + 1) & 1)) * MB * HD);

    {
      while (__hip_atomic_load(myProdFlag, __ATOMIC_RELAXED,
                               __HIP_MEMORY_SCOPE_AGENT) < (unsigned)t)
        __builtin_amdgcn_s_sleep(1);
#pragma unroll
      for (int it = 0; it < 4; ++it) {
        int q = it * 512 + tid;
        unsigned long long v = __hip_atomic_load(hin64 + q, __ATOMIC_RELAXED,
                                                 __HIP_MEMORY_SCOPE_AGENT);
        *(unsigned long long*)(&h_s[q >> 7][(q & 127) * 4]) = v;
      }
    }
    {
      int b = tid >> 5, c = tid & 31;
      const float* xr = x + ((size_t)(bg + b) * SEQ + t) * DX;
      x_s[b][c] = f2bf(xr[c]);
      if (c < 8) x_s[b][32 + c] = f2bf(xr[32 + c]);
      if (c == 8) x_s[b][40] = f2bf(ssr[(size_t)(bg + b) * SEQ + t]);
    }
    __syncthreads();  // B

    {
      const int m = lane & 15;
      f32x4 acc = {0.f, 0.f, 0.f, 0.f};
#pragma unroll
      for (int kt = 0; kt < 16; ++kt) {
        short8 a = *(const short8*)(&h_s[m][kt * 32 + kq]);
        acc = __builtin_amdgcn_mfma_f32_16x16x32_bf16(a, bfrag[kt], acc, 0, 0, 0);
      }
      short8 ax0 = *(const short8*)(&x_s[m][kq]);
      short8 ax1 = *(const short8*)(&x_s[m][32 + kq]);
      acc = __builtin_amdgcn_mfma_f32_16x16x32_bf16(ax0, bfrag[16], acc, 0, 0, 0);
      acc = __builtin_amdgcn_mfma_f32_16x16x32_bf16(ax1, bfrag[17], acc, 0, 0, 0);
#pragma unroll
      for (int r = 0; r < 4; ++r)
        gate_s[myGate][(lane >> 4) * 4 + r][ut * 16 + (lane & 15)] = acc[r];
    }
    __syncthreads();  // C

    float gi = sigm(gate_s[0][sb][su] + b_i);
    float gf_ = sigm(gate_s[1][sb][su] + b_f);
    float gg = tanhf(gate_s[2][sb][su] + b_g);
    float go = sigm(gate_s[3][sb][su] + b_o);
    creg = gf_ * creg + gi * gg;
    float h = go * tanhf(creg);
    {
      float hp = __shfl_xor(h, 1);
      if ((tid & 1) == 0) {
        uint32_t packed = (uint32_t)f2bf(h) | ((uint32_t)f2bf(hp) << 16);
        __hip_atomic_store(hout32 + ((sb * HD + u0 + su) >> 1), packed,
                           __ATOMIC_RELAXED, __HIP_MEMORY_SCOPE_AGENT);
      }
    }
    __syncthreads();  // D

    if (tid == 0)
      __hip_atomic_store(gf + wg * 16, (unsigned)(t + 1), __ATOMIC_RELAXED,
                         __HIP_MEMORY_SCOPE_AGENT);
    o2[((size_t)(bg + sb) * SEQ + t) * HD + u0 + su] = h;
  }
}

// ---------------- BN-coefficient kernel (1 block) ----------------
__global__ __launch_bounds__(512) void coef_kernel(
    const float* __restrict__ stats, const float* __restrict__ fc1_w,
    const float* __restrict__ fc1_b, const float* __restrict__ fc2_w,
    const float* __restrict__ fc2_b, const float* __restrict__ gamma,
    const float* __restrict__ beta, float* __restrict__ coef)
{
  __shared__ float r1[512], r2[512];
  const int j = threadIdx.x;
  const float inv_n = 1.0f / 32768.0f;
  float mean = stats[j] * inv_n;
  float var = stats[HD + j] * inv_n - mean * mean;
  float scale = gamma[j] * rsqrtf(var + 1e-5f);
  float shift = beta[j] - mean * scale;
  coef[j] = fc1_w[j] * scale;
  coef[HD + j] = fc2_w[j] * scale;
  r1[j] = fc1_w[j] * shift;
  r2[j] = fc2_w[j] * shift;
  __syncthreads();
  for (int s = 256; s > 0; s >>= 1) {
    if (j < s) { r1[j] += r1[j + s]; r2[j] += r2[j + s]; }
    __syncthreads();
  }
  if (j == 0) {
    coef[2 * HD] = r1[0] + fc1_b[0];
    coef[2 * HD + 1] = r2[0] + fc2_b[0];
  }
}

// ---------------- ssr kernel: one wave per (b,t) row ----------------
__global__ __launch_bounds__(256) void ssr_kernel(
    const float* __restrict__ o1, const float* __restrict__ coef,
    float* __restrict__ ssr_ws, float* __restrict__ dssr)
{
  const int row = blockIdx.x * 4 + (threadIdx.x >> 6);
  const int lane = threadIdx.x & 63;
  const float* p = o1 + (size_t)row * HD + lane * 8;
  float s1 = 0.f, s2 = 0.f;
#pragma unroll
  for (int j = 0; j < 8; ++j) {
    float v = p[j];
    s1 += v * coef[lane * 8 + j];
    s2 += v * coef[HD + lane * 8 + j];
  }
#pragma unroll
  for (int off = 32; off > 0; off >>= 1) {
    s1 += __shfl_down(s1, off);
    s2 += __shfl_down(s2, off);
  }
  if (lane == 0) {
    float sr = fmaxf(s1 + coef[2 * HD], 0.0f);
    float w = fabsf(sigm(s2 + coef[2 * HD + 1]));
    float v = sr * (1.0f + w);
    ssr_ws[row] = v;
    dssr[row] = v;
  }
}

// ---------------- fc3 output kernel ----------------
__global__ __launch_bounds__(256) void out_kernel(
    const float* __restrict__ o2, const float* __restrict__ fc3_w,
    const float* __restrict__ fc3_b, float* __restrict__ dout)
{
  const int row = blockIdx.x * 4 + (threadIdx.x >> 6);
  const int lane = threadIdx.x & 63;
  const float* p = o2 + (size_t)row * HD + lane * 8;
  float s = 0.f;
#pragma unroll
  for (int j = 0; j < 8; ++j) s += p[j] * fc3_w[lane * 8 + j];
#pragma unroll
  for (int off = 32; off > 0; off >>= 1) s += __shfl_down(s, off);
  if (lane == 0) dout[row] = fmaxf(s + fc3_b[0], 0.0f);
}

extern "C" void kernel_launch(void* const* d_in, const int* in_sizes, int n_in,
                              void* d_out, int out_size, void* d_ws, size_t ws_size,
                              hipStream_t stream) {
  (void)in_sizes; (void)n_in; (void)out_size; (void)ws_size;
  const float* x    = (const float*)d_in[0];
  const float* gWih = (const float*)d_in[1];
  const float* gWhh = (const float*)d_in[2];
  const float* gbih = (const float*)d_in[3];
  const float* gbhh = (const float*)d_in[4];
  const float* lWih = (const float*)d_in[5];
  const float* lWhh = (const float*)d_in[6];
  const float* lbih = (const float*)d_in[7];
  const float* lbhh = (const float*)d_in[8];
  const float* fc1w = (const float*)d_in[9];
  const float* fc1b = (const float*)d_in[10];
  const float* fc2w = (const float*)d_in[11];
  const float* fc2b = (const float*)d_in[12];
  const float* fc3w = (const float*)d_in[13];
  const float* fc3b = (const float*)d_in[14];
  const float* gam  = (const float*)d_in[15];
  const float* bet  = (const float*)d_in[16];
  float* out = (float*)d_out;

  char* ws = (char*)d_ws;
  unsigned* flags_g = (unsigned*)(ws + 0);            // 4 groups x 16 WG x 64B
  unsigned* flags_l = (unsigned*)(ws + 4096);
  float* stats      = (float*)(ws + 8192);            // 1024 f32
  float* coef       = (float*)(ws + 16384);           // 1026 f32
  float* ssr_ws     = (float*)(ws + 32768);           // 32768 f32
  unsigned short* hbuf_g = (unsigned short*)(ws + 262144);   // 128KB
  unsigned short* hbuf_l = (unsigned short*)(ws + 393216);   // 128KB
  float* o1 = (float*)(ws + 1048576);                 // 64MB
  float* o2 = o1 + (size_t)64 * SEQ * HD;             // 64MB

  hipMemsetAsync(ws, 0, 12288, stream);               // flags + stats
  hipMemsetAsync(ws + 262144, 0, 262144, stream);     // h exchange (h0=0)

  gru_kernel<<<dim3(64), dim3(512), 0, stream>>>(x, gWih, gWhh, gbih, gbhh,
                                                 flags_g, hbuf_g, o1, stats);
  coef_kernel<<<dim3(1), dim3(512), 0, stream>>>(stats, fc1w, fc1b, fc2w, fc2b,
                                                 gam, bet, coef);
  ssr_kernel<<<dim3(8192), dim3(256), 0, stream>>>(o1, coef, ssr_ws, out + 32768);
  lstm_kernel<<<dim3(64), dim3(512), 0, stream>>>(x, lWih, lWhh, lbih, lbhh, ssr_ws,
                                                  flags_l, hbuf_l, o2);
  out_kernel<<<dim3(8192), dim3(256), 0, stream>>>(o2, fc3w, fc3b, out);
}